// Round 1
// baseline (70498.431 us; speedup 1.0000x reference)
//
#include <hip/hip_runtime.h>
#include <hip/hip_bf16.h>

#define B_    64
#define Hh    56
#define Ww_   56
#define Cc    128
#define WINS  7
#define SHIFT 3
#define NHD   4
#define HD    32
#define Nn    49
#define NW    64
#define L_    (Hh * Ww_)        // 3136
#define MLPH  512
#define TOK   32                 // tokens per MLP block

// ---------- dtype hedge: ln gamma is all-ones; bf16 packs 0x3F80 twice ----------
__device__ __forceinline__ bool detect_bf(const void* ones) {
    return *((const unsigned*)ones) == 0x3F803F80u;
}
__device__ __forceinline__ float ldv(const void* p, int i, bool bf) {
    return bf ? __bfloat162float(((const __hip_bfloat16*)p)[i])
              : ((const float*)p)[i];
}
__device__ __forceinline__ void stv(void* p, int i, float v, bool bf) {
    if (bf) ((__hip_bfloat16*)p)[i] = __float2bfloat16(v);
    else    ((float*)p)[i] = v;
}

__device__ __forceinline__ float wsum(float v) {
    for (int off = 32; off; off >>= 1) v += __shfl_down(v, off, 64);
    return __shfl(v, 0, 64);
}
__device__ __forceinline__ float wmax(float v) {
    for (int off = 32; off; off >>= 1) v = fmaxf(v, __shfl_down(v, off, 64));
    return __shfl(v, 0, 64);
}

// region id for the SW-MSA mask (reference slices: [0,49),[49,53),[53,56))
__device__ __forceinline__ int region(int h, int w) {
    int a = (h < 49) ? 0 : ((h < 53) ? 1 : 2);
    int b = (w < 49) ? 0 : ((w < 53) ? 1 : 2);
    return a * 3 + b;
}

// ============ kernel 1: LN1 + shifted-window attention + proj + residual ============
// one block per (batch, window); writes x1 = x + attn_out into d_out
__global__ __launch_bounds__(256) void attn_kernel(
    const void* __restrict__ x,      const void* __restrict__ g1,
    const void* __restrict__ b1,     const void* __restrict__ qkv_w,
    const void* __restrict__ qkv_b,  const void* __restrict__ rpb,
    const void* __restrict__ proj_w, const void* __restrict__ proj_b,
    void* __restrict__ out)
{
    const bool bf = detect_bf(g1);
    __shared__ __hip_bfloat16 lno_s[Nn * Cc];    // LN output, later reused as attn O
    __shared__ __hip_bfloat16 qkv_s[Nn * 384];   // q|k|v per token
    __shared__ float          sc_s[Nn * Nn];     // one head's score matrix

    const int tid  = threadIdx.x;
    const int wv   = tid >> 6, lane = tid & 63;
    const int blk  = blockIdx.x;
    const int b    = blk >> 6, wi = blk & 63;
    const int wh   = wi >> 3,  ww = wi & 7;

    // ---- phase 1: gather shifted tokens + LN1 (one wave per token) ----
    for (int t = wv; t < Nn; t += 4) {
        int th = t / 7, tw = t - th * 7;
        int sh = wh * 7 + th + SHIFT; if (sh >= Hh)  sh -= Hh;
        int sw = ww * 7 + tw + SHIFT; if (sw >= Ww_) sw -= Ww_;
        int row = (b * L_ + sh * Ww_ + sw) * Cc;
        float v0 = ldv(x, row + lane, bf);
        float v1 = ldv(x, row + lane + 64, bf);
        float s  = wsum(v0 + v1);
        float ss = wsum(v0 * v0 + v1 * v1);
        float mu   = s * (1.f / 128.f);
        float var  = ss * (1.f / 128.f) - mu * mu;
        float rstd = rsqrtf(var + 1e-5f);
        lno_s[t * Cc + lane]      = __float2bfloat16((v0 - mu) * rstd * ldv(g1, lane, bf)      + ldv(b1, lane, bf));
        lno_s[t * Cc + lane + 64] = __float2bfloat16((v1 - mu) * rstd * ldv(g1, lane + 64, bf) + ldv(b1, lane + 64, bf));
    }
    __syncthreads();

    // ---- phase 2: qkv = ln @ qkv_w.T + qkv_b ----
    for (int idx = tid; idx < Nn * 384; idx += 256) {
        int t = idx / 384, j = idx - t * 384;
        float acc = ldv(qkv_b, j, bf);
        int wbase = j * Cc;
        for (int c = 0; c < Cc; c++)
            acc += __bfloat162float(lno_s[t * Cc + c]) * ldv(qkv_w, wbase + c, bf);
        qkv_s[t * 384 + j] = __float2bfloat16(acc);
    }
    __syncthreads();

    // ---- phase 3: per-head attention ----
    for (int nh = 0; nh < NHD; nh++) {
        // scores + bias + mask
        for (int idx = tid; idx < Nn * Nn; idx += 256) {
            int i = idx / Nn, j = idx - i * Nn;
            int qoff = i * 384 + nh * HD, koff = j * 384 + Cc + nh * HD;
            float acc = 0.f;
            for (int c = 0; c < HD; c++)
                acc += __bfloat162float(qkv_s[qoff + c]) * __bfloat162float(qkv_s[koff + c]);
            acc *= 0.17677669529663687f;   // 1/sqrt(32)
            int ih = i / 7, iw = i - ih * 7, jh = j / 7, jw = j - jh * 7;
            int rpi = (ih - jh + 6) * 13 + (iw - jw + 6);
            acc += ldv(rpb, rpi * NHD + nh, bf);
            int ri = region(wh * 7 + ih, ww * 7 + iw);
            int rj = region(wh * 7 + jh, ww * 7 + jw);
            if (ri != rj) acc -= 100.f;
            sc_s[idx] = acc;
        }
        __syncthreads();
        // softmax rows (wave per row)
        for (int t = wv; t < Nn; t += 4) {
            float v = (lane < Nn) ? sc_s[t * Nn + lane] : -1e30f;
            float m = wmax(v);
            float e = (lane < Nn) ? expf(v - m) : 0.f;
            float s = wsum(e);
            if (lane < Nn) sc_s[t * Nn + lane] = e / s;
        }
        __syncthreads();
        // O = P @ V  (write into lno_s, ln no longer needed)
        for (int idx = tid; idx < Nn * HD; idx += 256) {
            int i = idx / HD, c = idx - i * HD;
            float acc = 0.f;
            int vbase = 2 * Cc + nh * HD + c;
            for (int j = 0; j < Nn; j++)
                acc += sc_s[i * Nn + j] * __bfloat162float(qkv_s[j * 384 + vbase]);
            lno_s[i * Cc + nh * HD + c] = __float2bfloat16(acc);
        }
        __syncthreads();
    }

    // ---- phase 4: proj + residual, scatter back to original positions ----
    for (int idx = tid; idx < Nn * Cc; idx += 256) {
        int t = idx >> 7, c = idx & 127;
        float acc = ldv(proj_b, c, bf);
        int wbase = c * Cc;
        for (int d = 0; d < Cc; d++)
            acc += __bfloat162float(lno_s[t * Cc + d]) * ldv(proj_w, wbase + d, bf);
        int th = t / 7, tw = t - th * 7;
        int sh = wh * 7 + th + SHIFT; if (sh >= Hh)  sh -= Hh;
        int sw = ww * 7 + tw + SHIFT; if (sw >= Ww_) sw -= Ww_;
        int off = (b * L_ + sh * Ww_ + sw) * Cc + c;
        stv(out, off, ldv(x, off, bf) + acc, bf);
    }
}

// ============ kernel 2: LN2 + fc1 + GELU + fc2 + residual (in-place on d_out) ============
__global__ __launch_bounds__(256) void mlp_kernel(
    void* __restrict__ out,          const void* __restrict__ g2,
    const void* __restrict__ b2,     const void* __restrict__ fc1_w,
    const void* __restrict__ fc1_b,  const void* __restrict__ fc2_w,
    const void* __restrict__ fc2_b)
{
    const bool bf = detect_bf(g2);
    __shared__ float          x1_s[TOK * Cc];
    __shared__ __hip_bfloat16 ln2_s[TOK * Cc];
    __shared__ __hip_bfloat16 h1_s[TOK * MLPH];

    const int tid = threadIdx.x;
    const int wv = tid >> 6, lane = tid & 63;
    const int t0 = blockIdx.x * TOK;

    // load x1 rows + LN2 (wave per token)
    for (int t = wv; t < TOK; t += 4) {
        int row = (t0 + t) * Cc;
        float v0 = ldv(out, row + lane, bf);
        float v1 = ldv(out, row + lane + 64, bf);
        x1_s[t * Cc + lane]      = v0;
        x1_s[t * Cc + lane + 64] = v1;
        float s  = wsum(v0 + v1);
        float ss = wsum(v0 * v0 + v1 * v1);
        float mu   = s * (1.f / 128.f);
        float var  = ss * (1.f / 128.f) - mu * mu;
        float rstd = rsqrtf(var + 1e-5f);
        ln2_s[t * Cc + lane]      = __float2bfloat16((v0 - mu) * rstd * ldv(g2, lane, bf)      + ldv(b2, lane, bf));
        ln2_s[t * Cc + lane + 64] = __float2bfloat16((v1 - mu) * rstd * ldv(g2, lane + 64, bf) + ldv(b2, lane + 64, bf));
    }
    __syncthreads();

    // fc1 + exact GELU
    for (int idx = tid; idx < TOK * MLPH; idx += 256) {
        int t = idx >> 9, j = idx & 511;
        float acc = ldv(fc1_b, j, bf);
        int wbase = j * Cc;
        for (int c = 0; c < Cc; c++)
            acc += __bfloat162float(ln2_s[t * Cc + c]) * ldv(fc1_w, wbase + c, bf);
        h1_s[idx] = __float2bfloat16(0.5f * acc * (1.f + erff(acc * 0.70710678118654752f)));
    }
    __syncthreads();

    // fc2 + residual, in-place
    for (int idx = tid; idx < TOK * Cc; idx += 256) {
        int t = idx >> 7, c = idx & 127;
        float acc = ldv(fc2_b, c, bf);
        int wbase = c * MLPH;
        for (int d = 0; d < MLPH; d++)
            acc += __bfloat162float(h1_s[t * MLPH + d]) * ldv(fc2_w, wbase + d, bf);
        stv(out, (t0 + t) * Cc + c, x1_s[t * Cc + c] + acc, bf);
    }
}

extern "C" void kernel_launch(void* const* d_in, const int* in_sizes, int n_in,
                              void* d_out, int out_size, void* d_ws, size_t ws_size,
                              hipStream_t stream) {
    // inputs (setup_inputs order):
    // 0 x, 1 ln1_g, 2 ln1_b, 3 qkv_w, 4 qkv_b, 5 rpb_table, 6 proj_w, 7 proj_b,
    // 8 ln2_g, 9 ln2_b, 10 fc1_w, 11 fc1_b, 12 fc2_w, 13 fc2_b
    attn_kernel<<<B_ * NW, 256, 0, stream>>>(
        d_in[0], d_in[1], d_in[2], d_in[3], d_in[4], d_in[5], d_in[6], d_in[7], d_out);
    mlp_kernel<<<(B_ * L_) / TOK, 256, 0, stream>>>(
        d_out, d_in[8], d_in[9], d_in[10], d_in[11], d_in[12], d_in[13]);
}

// Round 2
// 1030.706 us; speedup vs baseline: 68.3982x; 68.3982x over previous
//
#include <hip/hip_runtime.h>
#include <math.h>

#define B_    64
#define Cc    128
#define L_    3136
#define MLPH  512

typedef __bf16 b8v __attribute__((ext_vector_type(8)));
typedef float  f4v __attribute__((ext_vector_type(4)));

__device__ __forceinline__ f4v mfma16(b8v a, b8v b, f4v c) {
    return __builtin_amdgcn_mfma_f32_16x16x32_bf16(a, b, c, 0, 0, 0);
}

__device__ __forceinline__ int region(int h, int w) {
    int a = (h < 49) ? 0 : ((h < 53) ? 1 : 2);
    int b = (w < 49) ? 0 : ((w < 53) ? 1 : 2);
    return a * 3 + b;
}

__device__ __forceinline__ float wsum64(float v) {
    for (int off = 32; off; off >>= 1) v += __shfl_down(v, off, 64);
    return __shfl(v, 0, 64);
}

// ---------- prep: fp32 weights -> bf16 in d_ws ----------
// layout (elements): [0,49152) qkv_w  [49152,65536) proj_w
//                    [65536,131072) fc1_w  [131072,196608) fc2_w
__global__ __launch_bounds__(256) void prep_kernel(
    const float* __restrict__ qkv_w, const float* __restrict__ proj_w,
    const float* __restrict__ fc1_w, const float* __restrict__ fc2_w,
    __bf16* __restrict__ ws)
{
    int i = blockIdx.x * 256 + threadIdx.x;
    if      (i <  49152) ws[i] = (__bf16)qkv_w[i];
    else if (i <  65536) ws[i] = (__bf16)proj_w[i - 49152];
    else if (i < 131072) ws[i] = (__bf16)fc1_w[i - 65536];
    else if (i < 196608) ws[i] = (__bf16)fc2_w[i - 131072];
}

// ---------- kernel 1: LN1 + SW-MSA + proj + residual ----------
// one block per (batch, window); 4 waves; writes x1 = x + attn into out (fp32)
__global__ __launch_bounds__(256) void attn_kernel(
    const float* __restrict__ x,   const float* __restrict__ g1,
    const float* __restrict__ b1,  const float* __restrict__ qkv_b,
    const float* __restrict__ rpb, const float* __restrict__ proj_b,
    const __bf16* __restrict__ wqkv, const __bf16* __restrict__ wproj,
    float* __restrict__ out)
{
    // strides padded so row-stride mod 32 dwords == 4 -> 2-way conflicts max (free)
    __shared__ __bf16 a_s[64 * 136];   // LN1 output, A operand
    __shared__ __bf16 o_s[64 * 136];   // attention output, A operand for proj
    __shared__ __bf16 qk_s[64 * 72];   // per-head: cols 0..31 = Q*scale, 32..63 = K
    __shared__ __bf16 vT_s[32 * 72];   // per-head: V transposed [d][token]
    __shared__ __bf16 p_s[64 * 72];    // softmax(P), A-layout staging

    const int tid  = threadIdx.x;
    const int w    = tid >> 6;
    const int lane = tid & 63;
    const int quad = lane >> 4;
    const int r16  = lane & 15;
    const int blk  = blockIdx.x;
    const int b    = blk >> 6, wi = blk & 63;
    const int wh   = wi >> 3,  ww = wi & 7;
    const float scale = 0.17677669529663687f;  // 1/sqrt(32)

    // ---- phase 1: gather shifted tokens + LN1 (wave per token) ----
    for (int t = w; t < 49; t += 4) {
        int th = t / 7, tw = t - th * 7;
        int sh = wh * 7 + th + 3; if (sh >= 56) sh -= 56;
        int sw = ww * 7 + tw + 3; if (sw >= 56) sw -= 56;
        int row = (b * L_ + sh * 56 + sw) * Cc;
        float v0 = x[row + lane], v1 = x[row + 64 + lane];
        float s  = wsum64(v0 + v1);
        float ss = wsum64(v0 * v0 + v1 * v1);
        float mu   = s * (1.f / 128.f);
        float rstd = rsqrtf(ss * (1.f / 128.f) - mu * mu + 1e-5f);
        a_s[t * 136 + lane]      = (__bf16)((v0 - mu) * rstd * g1[lane]      + b1[lane]);
        a_s[t * 136 + 64 + lane] = (__bf16)((v1 - mu) * rstd * g1[64 + lane] + b1[64 + lane]);
    }
    // zero pad rows 49..63 (K dims exact, only rows padded)
    for (int idx = tid; idx < 15 * 128; idx += 256) {
        int rr = idx >> 7, cc = idx & 127;
        a_s[(49 + rr) * 136 + cc] = (__bf16)0.f;
    }
    __syncthreads();

    // ---- per-head attention ----
    for (int h = 0; h < 4; h++) {
        // QKV GEMM for this head: C[64 x 96] = a_s @ W_h^T; 24 tile jobs
        for (int job = w; job < 24; job += 4) {
            int mt = job & 3, nt = job >> 2;
            int base = (nt < 2) ? (h * 32 + nt * 16)
                     : (nt < 4) ? (128 + h * 32 + (nt - 2) * 16)
                                : (256 + h * 32 + (nt - 4) * 16);
            const __bf16* ap = &a_s[(mt * 16 + r16) * 136 + quad * 8];
            const __bf16* bp = wqkv + (base + r16) * 128 + quad * 8;
            f4v acc = {0.f, 0.f, 0.f, 0.f};
            #pragma unroll
            for (int ks = 0; ks < 4; ks++)
                acc = mfma16(*(const b8v*)(ap + ks * 32), *(const b8v*)(bp + ks * 32), acc);
            float bias = qkv_b[base + r16];
            #pragma unroll
            for (int r = 0; r < 4; r++) {
                int m = mt * 16 + quad * 4 + r;
                float v = acc[r] + bias;
                if (nt < 2)      qk_s[m * 72 + nt * 16 + r16]            = (__bf16)(v * scale);
                else if (nt < 4) qk_s[m * 72 + 32 + (nt - 2) * 16 + r16] = (__bf16)v;
                else             vT_s[((nt - 4) * 16 + r16) * 72 + m]    = (__bf16)v;
            }
        }
        __syncthreads();

        // S = Q @ K^T : wave w owns row strip [16w,16w+16); K=32 -> 1 MFMA/tile
        b8v qf = *(const b8v*)&qk_s[(w * 16 + r16) * 72 + quad * 8];
        f4v s[4];
        #pragma unroll
        for (int nt = 0; nt < 4; nt++) {
            b8v kf = *(const b8v*)&qk_s[(nt * 16 + r16) * 72 + 32 + quad * 8];
            f4v z = {0.f, 0.f, 0.f, 0.f};
            s[nt] = mfma16(qf, kf, z);
        }
        // bias + shift-mask (in regs, D layout: row=16w+quad*4+r, col=nt*16+r16)
        #pragma unroll
        for (int nt = 0; nt < 4; nt++) {
            int j = nt * 16 + r16;
            if (j < 49) {
                int jh = j / 7, jw = j - jh * 7;
                int rj = region(wh * 7 + jh, ww * 7 + jw);
                #pragma unroll
                for (int r = 0; r < 4; r++) {
                    int i = w * 16 + quad * 4 + r;
                    if (i < 49) {
                        int ih = i / 7, iw = i - ih * 7;
                        int rpi = (ih - jh + 6) * 13 + (iw - jw + 6);
                        float bias = rpb[rpi * 4 + h];
                        int ri = region(wh * 7 + ih, ww * 7 + iw);
                        s[nt][r] += (ri != rj) ? (bias - 100.f) : bias;
                    }
                }
            } else {
                #pragma unroll
                for (int r = 0; r < 4; r++) s[nt][r] = -1e30f;
            }
        }
        // softmax per row (row lives in one 16-lane quad x 4 nt regs)
        #pragma unroll
        for (int r = 0; r < 4; r++) {
            float mx = fmaxf(fmaxf(s[0][r], s[1][r]), fmaxf(s[2][r], s[3][r]));
            #pragma unroll
            for (int mk = 1; mk < 16; mk <<= 1) mx = fmaxf(mx, __shfl_xor(mx, mk, 64));
            float e0 = expf(s[0][r] - mx), e1 = expf(s[1][r] - mx);
            float e2 = expf(s[2][r] - mx), e3 = expf(s[3][r] - mx);
            float sm = e0 + e1 + e2 + e3;
            #pragma unroll
            for (int mk = 1; mk < 16; mk <<= 1) sm += __shfl_xor(sm, mk, 64);
            float inv = 1.f / sm;
            s[0][r] = e0 * inv; s[1][r] = e1 * inv; s[2][r] = e2 * inv; s[3][r] = e3 * inv;
        }
        // P -> LDS (layout transform D->A); wave w only writes/reads its own strip
        #pragma unroll
        for (int nt = 0; nt < 4; nt++)
            #pragma unroll
            for (int r = 0; r < 4; r++)
                p_s[(w * 16 + quad * 4 + r) * 72 + nt * 16 + r16] = (__bf16)s[nt][r];

        // O = P @ V : M-strip w, N=32 (2 tiles), K=64 (2 steps)
        #pragma unroll
        for (int nt = 0; nt < 2; nt++) {
            f4v acc = {0.f, 0.f, 0.f, 0.f};
            #pragma unroll
            for (int ks = 0; ks < 2; ks++) {
                b8v pf = *(const b8v*)&p_s[(w * 16 + r16) * 72 + ks * 32 + quad * 8];
                b8v vf = *(const b8v*)&vT_s[(nt * 16 + r16) * 72 + ks * 32 + quad * 8];
                acc = mfma16(pf, vf, acc);
            }
            #pragma unroll
            for (int r = 0; r < 4; r++)
                o_s[(w * 16 + quad * 4 + r) * 136 + h * 32 + nt * 16 + r16] = (__bf16)acc[r];
        }
        __syncthreads();   // protect qk_s/vT_s before next head overwrites
    }

    // ---- proj + residual, scatter to original (unshifted) positions ----
    for (int job = w; job < 32; job += 4) {
        int mt = job >> 3, nt = job & 7;
        const __bf16* ap = &o_s[(mt * 16 + r16) * 136 + quad * 8];
        const __bf16* bp = wproj + (nt * 16 + r16) * 128 + quad * 8;
        f4v acc = {0.f, 0.f, 0.f, 0.f};
        #pragma unroll
        for (int ks = 0; ks < 4; ks++)
            acc = mfma16(*(const b8v*)(ap + ks * 32), *(const b8v*)(bp + ks * 32), acc);
        int col = nt * 16 + r16;
        float pb = proj_b[col];
        #pragma unroll
        for (int r = 0; r < 4; r++) {
            int t = mt * 16 + quad * 4 + r;
            if (t < 49) {
                int th = t / 7, tw = t - th * 7;
                int sh = wh * 7 + th + 3; if (sh >= 56) sh -= 56;
                int sw = ww * 7 + tw + 3; if (sw >= 56) sw -= 56;
                int off = (b * L_ + sh * 56 + sw) * Cc + col;
                out[off] = x[off] + acc[r] + pb;
            }
        }
    }
}

// ---------- kernel 2: LN2 + fc1 + GELU + fc2 + residual (in place on out) ----------
__global__ __launch_bounds__(256) void mlp_kernel(
    float* __restrict__ out, const float* __restrict__ g2, const float* __restrict__ b2,
    const float* __restrict__ fc1_b, const float* __restrict__ fc2_b,
    const __bf16* __restrict__ wfc1, const __bf16* __restrict__ wfc2)
{
    __shared__ __bf16 a_s[32 * 136];
    __shared__ __bf16 h1_s[32 * 520];
    const int tid = threadIdx.x, w = tid >> 6, lane = tid & 63;
    const int quad = lane >> 4, r16 = lane & 15;
    const int t0 = blockIdx.x * 32;

    // LN2 (wave per token)
    for (int t = w; t < 32; t += 4) {
        int row = (t0 + t) * Cc;
        float v0 = out[row + lane], v1 = out[row + 64 + lane];
        float s  = wsum64(v0 + v1);
        float ss = wsum64(v0 * v0 + v1 * v1);
        float mu   = s * (1.f / 128.f);
        float rstd = rsqrtf(ss * (1.f / 128.f) - mu * mu + 1e-5f);
        a_s[t * 136 + lane]      = (__bf16)((v0 - mu) * rstd * g2[lane]      + b2[lane]);
        a_s[t * 136 + 64 + lane] = (__bf16)((v1 - mu) * rstd * g2[64 + lane] + b2[64 + lane]);
    }
    __syncthreads();

    // fc1 + exact GELU: 64 jobs (2 mt x 32 nt), K=128
    for (int job = w; job < 64; job += 4) {
        int mt = job & 1, nt = job >> 1;
        const __bf16* ap = &a_s[(mt * 16 + r16) * 136 + quad * 8];
        const __bf16* bp = wfc1 + (nt * 16 + r16) * 128 + quad * 8;
        f4v acc = {0.f, 0.f, 0.f, 0.f};
        #pragma unroll
        for (int ks = 0; ks < 4; ks++)
            acc = mfma16(*(const b8v*)(ap + ks * 32), *(const b8v*)(bp + ks * 32), acc);
        float bias = fc1_b[nt * 16 + r16];
        #pragma unroll
        for (int r = 0; r < 4; r++) {
            float v = acc[r] + bias;
            v = 0.5f * v * (1.f + erff(v * 0.70710678118654752f));
            h1_s[(mt * 16 + quad * 4 + r) * 520 + nt * 16 + r16] = (__bf16)v;
        }
    }
    __syncthreads();

    // fc2 + residual: 16 jobs (2 mt x 8 nt), K=512
    for (int job = w; job < 16; job += 4) {
        int mt = job & 1, nt = job >> 1;
        const __bf16* ap = &h1_s[(mt * 16 + r16) * 520 + quad * 8];
        const __bf16* bp = wfc2 + (nt * 16 + r16) * 512 + quad * 8;
        f4v acc = {0.f, 0.f, 0.f, 0.f};
        #pragma unroll
        for (int ks = 0; ks < 16; ks++)
            acc = mfma16(*(const b8v*)(ap + ks * 32), *(const b8v*)(bp + ks * 32), acc);
        int col = nt * 16 + r16;
        float bias = fc2_b[col];
        #pragma unroll
        for (int r = 0; r < 4; r++) {
            int off = (t0 + mt * 16 + quad * 4 + r) * Cc + col;
            out[off] = out[off] + acc[r] + bias;
        }
    }
}

extern "C" void kernel_launch(void* const* d_in, const int* in_sizes, int n_in,
                              void* d_out, int out_size, void* d_ws, size_t ws_size,
                              hipStream_t stream) {
    // 0 x, 1 ln1_g, 2 ln1_b, 3 qkv_w, 4 qkv_b, 5 rpb_table, 6 proj_w, 7 proj_b,
    // 8 ln2_g, 9 ln2_b, 10 fc1_w, 11 fc1_b, 12 fc2_w, 13 fc2_b
    __bf16* wsb = (__bf16*)d_ws;
    prep_kernel<<<768, 256, 0, stream>>>(
        (const float*)d_in[3], (const float*)d_in[6],
        (const float*)d_in[10], (const float*)d_in[12], wsb);
    attn_kernel<<<B_ * 64, 256, 0, stream>>>(
        (const float*)d_in[0], (const float*)d_in[1], (const float*)d_in[2],
        (const float*)d_in[4], (const float*)d_in[5], (const float*)d_in[7],
        wsb, wsb + 49152, (float*)d_out);
    mlp_kernel<<<(B_ * L_) / 32, 256, 0, stream>>>(
        (float*)d_out, (const float*)d_in[8], (const float*)d_in[9],
        (const float*)d_in[11], (const float*)d_in[13],
        wsb + 65536, wsb + 131072);
}

// Round 3
// 883.046 us; speedup vs baseline: 79.8355x; 1.1672x over previous
//
#include <hip/hip_runtime.h>
#include <math.h>

#define B_  64
#define Cc  128
#define L_  3136

typedef __bf16 b8v __attribute__((ext_vector_type(8)));
typedef float  f4v __attribute__((ext_vector_type(4)));

__device__ __forceinline__ f4v mfma16(b8v a, b8v b, f4v c) {
    return __builtin_amdgcn_mfma_f32_16x16x32_bf16(a, b, c, 0, 0, 0);
}
__device__ __forceinline__ int region(int h, int w) {
    int a = (h < 49) ? 0 : ((h < 53) ? 1 : 2);
    int b = (w < 49) ? 0 : ((w < 53) ? 1 : 2);
    return a * 3 + b;
}

// ws layout: bf16 weights [0,196608) elems; biasmask f32[4][4][64][64] at byte 393216
__global__ __launch_bounds__(256) void prep_kernel(
    const float* __restrict__ qkv_w, const float* __restrict__ proj_w,
    const float* __restrict__ fc1_w, const float* __restrict__ fc2_w,
    const float* __restrict__ rpb,
    __bf16* __restrict__ wsb, float* __restrict__ bm)
{
    int i = blockIdx.x * 256 + threadIdx.x;
    if      (i <  49152) wsb[i] = (__bf16)qkv_w[i];
    else if (i <  65536) wsb[i] = (__bf16)proj_w[i - 49152];
    else if (i < 131072) wsb[i] = (__bf16)fc1_w[i - 65536];
    else if (i < 196608) wsb[i] = (__bf16)fc2_w[i - 131072];
    else {
        int idx = i - 196608;  // ((wt*4+h)*64+ii)*64+jj
        int jj = idx & 63, ii = (idx >> 6) & 63, h = (idx >> 12) & 3, wt = idx >> 14;
        float v;
        if (jj >= 49)      v = -1e30f;
        else if (ii >= 49) v = 0.f;
        else {
            int ih = ii / 7, iw = ii - ih * 7, jh = jj / 7, jw = jj - jh * 7;
            v = rpb[((ih - jh + 6) * 13 + (iw - jw + 6)) * 4 + h];
            int WH = (wt & 2) ? 49 : 0, WW = (wt & 1) ? 49 : 0;
            if (region(WH + ih, WW + iw) != region(WH + jh, WW + jw)) v -= 100.f;
        }
        bm[idx] = v;
    }
}

// ---- fused: LN1 + SW-MSA + proj + residual + LN2 + MLP + residual ----
// one block per (batch, window); LDS 50.7KB -> 3 blocks/CU
__global__ __launch_bounds__(256, 3) void swin_kernel(
    const float* __restrict__ x,
    const float* __restrict__ g1, const float* __restrict__ b1,
    const float* __restrict__ qkv_b, const float* __restrict__ proj_b,
    const float* __restrict__ g2, const float* __restrict__ b2,
    const float* __restrict__ fc1_b, const float* __restrict__ fc2_b,
    const __bf16* __restrict__ wqkv, const __bf16* __restrict__ wproj,
    const __bf16* __restrict__ wfc1, const __bf16* __restrict__ wfc2,
    const float* __restrict__ bm,
    float* __restrict__ out)
{
    __shared__ __bf16 a_s[64 * 136];               // LN1 out -> x1 -> LN2 out
    __shared__ __align__(16) char u_s[33280];      // phase union
    __bf16* QKs = (__bf16*)u_s;                    // 64 x 72 (Q | K)
    __bf16* VTs = (__bf16*)(u_s + 9216);           // 32 x 72 (V^T)
    __bf16* PSs = (__bf16*)(u_s + 13824);          // 64 x 72 (softmax P)
    __bf16* OSs = (__bf16*)u_s;                    // 64 x 136 (attn O)
    __bf16* H1s = (__bf16*)u_s;                    // 32 x 520 (fc1 chunk)

    const int tid = threadIdx.x, w = tid >> 6, lane = tid & 63;
    const int quad = lane >> 4, r16 = lane & 15;
    const int blk = blockIdx.x, b = blk >> 6, wi = blk & 63;
    const int wh = wi >> 3, ww = wi & 7;
    const int wt = ((wh == 7) ? 2 : 0) | ((ww == 7) ? 1 : 0);
    const float scale = 0.17677669529663687f;  // 1/sqrt(32)

    // ---- LN1 with shifted gather (2 tokens/iter, 4 interleaved shfl chains) ----
    for (int t = w; t < 49; t += 8) {
        int t2 = t + 4; bool has2 = (t2 < 49);
        int th = t / 7, tw = t - th * 7;
        int sh = wh * 7 + th + 3; if (sh >= 56) sh -= 56;
        int sw = ww * 7 + tw + 3; if (sw >= 56) sw -= 56;
        int rowA = (b * L_ + sh * 56 + sw) * Cc;
        int rowB = rowA;
        if (has2) {
            int th2 = t2 / 7, tw2 = t2 - th2 * 7;
            int sh2 = wh * 7 + th2 + 3; if (sh2 >= 56) sh2 -= 56;
            int sw2 = ww * 7 + tw2 + 3; if (sw2 >= 56) sw2 -= 56;
            rowB = (b * L_ + sh2 * 56 + sw2) * Cc;
        }
        float a0 = x[rowA + lane], a1 = x[rowA + 64 + lane];
        float c0 = x[rowB + lane], c1 = x[rowB + 64 + lane];
        float sA = a0 + a1, qA = a0 * a0 + a1 * a1;
        float sB = c0 + c1, qB = c0 * c0 + c1 * c1;
        for (int off = 32; off; off >>= 1) {
            sA += __shfl_down(sA, off, 64); qA += __shfl_down(qA, off, 64);
            sB += __shfl_down(sB, off, 64); qB += __shfl_down(qB, off, 64);
        }
        sA = __shfl(sA, 0, 64); qA = __shfl(qA, 0, 64);
        sB = __shfl(sB, 0, 64); qB = __shfl(qB, 0, 64);
        {
            float mu = sA * (1.f / 128.f);
            float rs = rsqrtf(qA * (1.f / 128.f) - mu * mu + 1e-5f);
            a_s[t * 136 + lane]      = (__bf16)((a0 - mu) * rs * g1[lane]      + b1[lane]);
            a_s[t * 136 + 64 + lane] = (__bf16)((a1 - mu) * rs * g1[64 + lane] + b1[64 + lane]);
        }
        if (has2) {
            float mu = sB * (1.f / 128.f);
            float rs = rsqrtf(qB * (1.f / 128.f) - mu * mu + 1e-5f);
            a_s[t2 * 136 + lane]      = (__bf16)((c0 - mu) * rs * g1[lane]      + b1[lane]);
            a_s[t2 * 136 + 64 + lane] = (__bf16)((c1 - mu) * rs * g1[64 + lane] + b1[64 + lane]);
        }
    }
    for (int idx = tid; idx < 15 * 128; idx += 256) {
        int rr = idx >> 7, cc = idx & 127;
        a_s[(49 + rr) * 136 + cc] = (__bf16)0.f;
    }
    __syncthreads();

    // ---- attention: O accumulates in registers ----
    f4v o_acc[4][2];
    #pragma unroll
    for (int h = 0; h < 4; h++)
        #pragma unroll
        for (int n = 0; n < 2; n++)
            o_acc[h][n] = (f4v){0.f, 0.f, 0.f, 0.f};

    const float* bmw = bm + wt * 4 * 4096;

    for (int h = 0; h < 4; h++) {
        // QKV for this head: wave w owns M-strip mt=w; nt=0..5 (Q,Q,K,K,V,V)
        {
            const __bf16* ap = &a_s[(w * 16 + r16) * 136 + quad * 8];
            b8v A0 = *(const b8v*)(ap);
            b8v A1 = *(const b8v*)(ap + 32);
            b8v A2 = *(const b8v*)(ap + 64);
            b8v A3 = *(const b8v*)(ap + 96);
            #pragma unroll
            for (int nt = 0; nt < 6; nt++) {
                int base = (nt < 2) ? (h * 32 + nt * 16)
                         : (nt < 4) ? (128 + h * 32 + (nt - 2) * 16)
                                    : (256 + h * 32 + (nt - 4) * 16);
                const __bf16* bp = wqkv + (base + r16) * 128 + quad * 8;
                f4v acc = {0.f, 0.f, 0.f, 0.f};
                acc = mfma16(A0, *(const b8v*)(bp),      acc);
                acc = mfma16(A1, *(const b8v*)(bp + 32), acc);
                acc = mfma16(A2, *(const b8v*)(bp + 64), acc);
                acc = mfma16(A3, *(const b8v*)(bp + 96), acc);
                float bias = qkv_b[base + r16];
                #pragma unroll
                for (int r = 0; r < 4; r++) {
                    int m = w * 16 + quad * 4 + r;
                    float v = acc[r] + bias;
                    if (nt < 2)      QKs[m * 72 + nt * 16 + r16]            = (__bf16)(v * scale);
                    else if (nt < 4) QKs[m * 72 + 32 + (nt - 2) * 16 + r16] = (__bf16)v;
                    else             VTs[((nt - 4) * 16 + r16) * 72 + m]    = (__bf16)v;
                }
            }
        }
        __syncthreads();

        // S = Q K^T + (bias+mask table)
        f4v s[4];
        {
            b8v qf = *(const b8v*)&QKs[(w * 16 + r16) * 72 + quad * 8];
            #pragma unroll
            for (int nt = 0; nt < 4; nt++) {
                b8v kf = *(const b8v*)&QKs[(nt * 16 + r16) * 72 + 32 + quad * 8];
                f4v z = {0.f, 0.f, 0.f, 0.f};
                s[nt] = mfma16(qf, kf, z);
            }
            const float* bmp = bmw + h * 4096 + (w * 16 + quad * 4) * 64 + r16;
            #pragma unroll
            for (int nt = 0; nt < 4; nt++)
                #pragma unroll
                for (int r = 0; r < 4; r++)
                    s[nt][r] += bmp[r * 64 + nt * 16];
        }
        // softmax: 4 rows, shfl chains interleaved
        {
            float mx[4], sm[4];
            #pragma unroll
            for (int r = 0; r < 4; r++)
                mx[r] = fmaxf(fmaxf(s[0][r], s[1][r]), fmaxf(s[2][r], s[3][r]));
            #pragma unroll
            for (int mk = 1; mk < 16; mk <<= 1)
                #pragma unroll
                for (int r = 0; r < 4; r++)
                    mx[r] = fmaxf(mx[r], __shfl_xor(mx[r], mk, 64));
            #pragma unroll
            for (int r = 0; r < 4; r++) {
                s[0][r] = expf(s[0][r] - mx[r]);
                s[1][r] = expf(s[1][r] - mx[r]);
                s[2][r] = expf(s[2][r] - mx[r]);
                s[3][r] = expf(s[3][r] - mx[r]);
                sm[r] = s[0][r] + s[1][r] + s[2][r] + s[3][r];
            }
            #pragma unroll
            for (int mk = 1; mk < 16; mk <<= 1)
                #pragma unroll
                for (int r = 0; r < 4; r++)
                    sm[r] += __shfl_xor(sm[r], mk, 64);
            #pragma unroll
            for (int r = 0; r < 4; r++) {
                float inv = 1.f / sm[r];
                s[0][r] *= inv; s[1][r] *= inv; s[2][r] *= inv; s[3][r] *= inv;
            }
        }
        // P -> LDS (D->A transform, wave-local strip)
        #pragma unroll
        for (int nt = 0; nt < 4; nt++)
            #pragma unroll
            for (int r = 0; r < 4; r++)
                PSs[(w * 16 + quad * 4 + r) * 72 + nt * 16 + r16] = (__bf16)s[nt][r];

        // O += P V (register accumulation)
        #pragma unroll
        for (int nt = 0; nt < 2; nt++)
            #pragma unroll
            for (int ks = 0; ks < 2; ks++) {
                b8v pf = *(const b8v*)&PSs[(w * 16 + r16) * 72 + ks * 32 + quad * 8];
                b8v vf = *(const b8v*)&VTs[(nt * 16 + r16) * 72 + ks * 32 + quad * 8];
                o_acc[h][nt] = mfma16(pf, vf, o_acc[h][nt]);
            }
        __syncthreads();
    }

    // O regs -> LDS (union now free)
    #pragma unroll
    for (int h = 0; h < 4; h++)
        #pragma unroll
        for (int nt = 0; nt < 2; nt++)
            #pragma unroll
            for (int r = 0; r < 4; r++)
                OSs[(w * 16 + quad * 4 + r) * 136 + h * 32 + nt * 16 + r16] = (__bf16)o_acc[h][nt][r];
    __syncthreads();

    // ---- proj + residual: x1 -> out (fp32) and a_s (bf16) ----
    {
        const __bf16* ap = &OSs[(w * 16 + r16) * 136 + quad * 8];
        b8v A0 = *(const b8v*)(ap);
        b8v A1 = *(const b8v*)(ap + 32);
        b8v A2 = *(const b8v*)(ap + 64);
        b8v A3 = *(const b8v*)(ap + 96);
        #pragma unroll
        for (int nt = 0; nt < 8; nt++) {
            const __bf16* bp = wproj + (nt * 16 + r16) * 128 + quad * 8;
            f4v acc = {0.f, 0.f, 0.f, 0.f};
            acc = mfma16(A0, *(const b8v*)(bp),      acc);
            acc = mfma16(A1, *(const b8v*)(bp + 32), acc);
            acc = mfma16(A2, *(const b8v*)(bp + 64), acc);
            acc = mfma16(A3, *(const b8v*)(bp + 96), acc);
            int col = nt * 16 + r16;
            float pb = proj_b[col];
            #pragma unroll
            for (int r = 0; r < 4; r++) {
                int t = w * 16 + quad * 4 + r;
                float x1v = 0.f;
                if (t < 49) {
                    int th = t / 7, tw = t - th * 7;
                    int sh = wh * 7 + th + 3; if (sh >= 56) sh -= 56;
                    int sw = ww * 7 + tw + 3; if (sw >= 56) sw -= 56;
                    int off = (b * L_ + sh * 56 + sw) * Cc + col;
                    x1v = x[off] + acc[r] + pb;
                    out[off] = x1v;
                }
                a_s[t * 136 + col] = (__bf16)x1v;
            }
        }
    }
    __syncthreads();

    // ---- LN2 in place on a_s (rows >=49 stay zero) ----
    for (int t = w; t < 49; t += 8) {
        int t2 = t + 4; bool has2 = (t2 < 49);
        int tB = has2 ? t2 : t;
        float a0 = (float)a_s[t * 136 + lane],  a1 = (float)a_s[t * 136 + 64 + lane];
        float c0 = (float)a_s[tB * 136 + lane], c1 = (float)a_s[tB * 136 + 64 + lane];
        float sA = a0 + a1, qA = a0 * a0 + a1 * a1;
        float sB = c0 + c1, qB = c0 * c0 + c1 * c1;
        for (int off = 32; off; off >>= 1) {
            sA += __shfl_down(sA, off, 64); qA += __shfl_down(qA, off, 64);
            sB += __shfl_down(sB, off, 64); qB += __shfl_down(qB, off, 64);
        }
        sA = __shfl(sA, 0, 64); qA = __shfl(qA, 0, 64);
        sB = __shfl(sB, 0, 64); qB = __shfl(qB, 0, 64);
        {
            float mu = sA * (1.f / 128.f);
            float rs = rsqrtf(qA * (1.f / 128.f) - mu * mu + 1e-5f);
            a_s[t * 136 + lane]      = (__bf16)((a0 - mu) * rs * g2[lane]      + b2[lane]);
            a_s[t * 136 + 64 + lane] = (__bf16)((a1 - mu) * rs * g2[64 + lane] + b2[64 + lane]);
        }
        if (has2) {
            float mu = sB * (1.f / 128.f);
            float rs = rsqrtf(qB * (1.f / 128.f) - mu * mu + 1e-5f);
            a_s[t2 * 136 + lane]      = (__bf16)((c0 - mu) * rs * g2[lane]      + b2[lane]);
            a_s[t2 * 136 + 64 + lane] = (__bf16)((c1 - mu) * rs * g2[64 + lane] + b2[64 + lane]);
        }
    }
    __syncthreads();

    // ---- MLP: 2 chunks of 32 rows; h1 in union ----
    #pragma unroll
    for (int ch = 0; ch < 2; ch++) {
        // fc1 + GELU: wave w -> nt = w*8..w*8+7, both 16-row M-tiles share B
        {
            const __bf16* ap0 = &a_s[(ch * 32 + r16) * 136 + quad * 8];
            const __bf16* ap1 = &a_s[(ch * 32 + 16 + r16) * 136 + quad * 8];
            b8v A00 = *(const b8v*)(ap0), A01 = *(const b8v*)(ap0 + 32),
                A02 = *(const b8v*)(ap0 + 64), A03 = *(const b8v*)(ap0 + 96);
            b8v A10 = *(const b8v*)(ap1), A11 = *(const b8v*)(ap1 + 32),
                A12 = *(const b8v*)(ap1 + 64), A13 = *(const b8v*)(ap1 + 96);
            #pragma unroll
            for (int k = 0; k < 8; k++) {
                int nt = w * 8 + k;
                const __bf16* bp = wfc1 + (nt * 16 + r16) * 128 + quad * 8;
                b8v Bf0 = *(const b8v*)(bp), Bf1 = *(const b8v*)(bp + 32),
                    Bf2 = *(const b8v*)(bp + 64), Bf3 = *(const b8v*)(bp + 96);
                f4v acc0 = {0.f, 0.f, 0.f, 0.f}, acc1 = {0.f, 0.f, 0.f, 0.f};
                acc0 = mfma16(A00, Bf0, acc0); acc1 = mfma16(A10, Bf0, acc1);
                acc0 = mfma16(A01, Bf1, acc0); acc1 = mfma16(A11, Bf1, acc1);
                acc0 = mfma16(A02, Bf2, acc0); acc1 = mfma16(A12, Bf2, acc1);
                acc0 = mfma16(A03, Bf3, acc0); acc1 = mfma16(A13, Bf3, acc1);
                float bias = fc1_b[nt * 16 + r16];
                #pragma unroll
                for (int r = 0; r < 4; r++) {
                    float v0 = acc0[r] + bias;
                    float v1 = acc1[r] + bias;
                    v0 = 0.5f * v0 * (1.f + erff(v0 * 0.70710678118654752f));
                    v1 = 0.5f * v1 * (1.f + erff(v1 * 0.70710678118654752f));
                    H1s[(quad * 4 + r) * 520 + nt * 16 + r16]        = (__bf16)v0;
                    H1s[(16 + quad * 4 + r) * 520 + nt * 16 + r16]   = (__bf16)v1;
                }
            }
        }
        __syncthreads();
        // fc2 + residual RMW: wave w -> nt = {w, w+4}, both M-tiles; 4 accs
        {
            f4v acc00 = {0.f,0.f,0.f,0.f}, acc01 = {0.f,0.f,0.f,0.f};
            f4v acc10 = {0.f,0.f,0.f,0.f}, acc11 = {0.f,0.f,0.f,0.f};
            const __bf16* bp0 = wfc2 + (w * 16 + r16) * 512 + quad * 8;
            const __bf16* bp1 = wfc2 + ((w + 4) * 16 + r16) * 512 + quad * 8;
            const __bf16* ap0 = &H1s[r16 * 520 + quad * 8];
            const __bf16* ap1 = &H1s[(16 + r16) * 520 + quad * 8];
            #pragma unroll
            for (int ks = 0; ks < 16; ks++) {
                b8v Af0 = *(const b8v*)(ap0 + ks * 32);
                b8v Af1 = *(const b8v*)(ap1 + ks * 32);
                b8v Bf0 = *(const b8v*)(bp0 + ks * 32);
                b8v Bf1 = *(const b8v*)(bp1 + ks * 32);
                acc00 = mfma16(Af0, Bf0, acc00);
                acc10 = mfma16(Af1, Bf0, acc10);
                acc01 = mfma16(Af0, Bf1, acc01);
                acc11 = mfma16(Af1, Bf1, acc11);
            }
            float fb0 = fc2_b[w * 16 + r16];
            float fb1 = fc2_b[64 + w * 16 + r16];
            #pragma unroll
            for (int mt = 0; mt < 2; mt++) {
                #pragma unroll
                for (int r = 0; r < 4; r++) {
                    int t = ch * 32 + mt * 16 + quad * 4 + r;
                    if (t < 49) {
                        int th = t / 7, tw = t - th * 7;
                        int sh = wh * 7 + th + 3; if (sh >= 56) sh -= 56;
                        int sw = ww * 7 + tw + 3; if (sw >= 56) sw -= 56;
                        int off = (b * L_ + sh * 56 + sw) * Cc;
                        float v0 = mt ? acc10[r] : acc00[r];
                        float v1 = mt ? acc11[r] : acc01[r];
                        out[off + w * 16 + r16]      += v0 + fb0;
                        out[off + 64 + w * 16 + r16] += v1 + fb1;
                    }
                }
            }
        }
        __syncthreads();
    }
}

extern "C" void kernel_launch(void* const* d_in, const int* in_sizes, int n_in,
                              void* d_out, int out_size, void* d_ws, size_t ws_size,
                              hipStream_t stream) {
    // 0 x, 1 ln1_g, 2 ln1_b, 3 qkv_w, 4 qkv_b, 5 rpb_table, 6 proj_w, 7 proj_b,
    // 8 ln2_g, 9 ln2_b, 10 fc1_w, 11 fc1_b, 12 fc2_w, 13 fc2_b
    __bf16* wsb = (__bf16*)d_ws;
    float*  bmp = (float*)((char*)d_ws + 393216);
    prep_kernel<<<1024, 256, 0, stream>>>(
        (const float*)d_in[3], (const float*)d_in[6],
        (const float*)d_in[10], (const float*)d_in[12],
        (const float*)d_in[5], wsb, bmp);
    swin_kernel<<<B_ * 64, 256, 0, stream>>>(
        (const float*)d_in[0],
        (const float*)d_in[1], (const float*)d_in[2],
        (const float*)d_in[4], (const float*)d_in[7],
        (const float*)d_in[8], (const float*)d_in[9],
        (const float*)d_in[11], (const float*)d_in[13],
        wsb, wsb + 49152, wsb + 65536, wsb + 131072,
        bmp, (float*)d_out);
}